// Round 1
// baseline (445.245 us; speedup 1.0000x reference)
//
#include <hip/hip_runtime.h>

// AbstractLinear: y = x @ W.T + b  (256x8192x8192, bf16 MFMA)
//                 IBP bounds fused on W staging regs (fp32):
//                 P = W@(l+h), R = |W|@(h-l); low=.5(P-R)+b, high=.5(P+R)+b
// R5: register pipeline 2 -> 4 slots. Counters showed latency-bound
//     (MfmaUtil 7%, VALU 12%, HBM 30%, occ 21% grid-capped at 2 blk/CU):
//     convert_write's vmcnt waited on loads issued 1 phase earlier.
//     4 slots push the prefetch distance to 3 phases (~3 barriers of work
//     in flight). VGPR 80 -> ~200, still under the launch_bounds(256,2)
//     cap of 256. R3/R4 verified structure (swizzle, coalesced staging,
//     lgkmcnt-only barrier, epilogues) unchanged.
#define M_TOTAL 256
#define N_TOTAL 8192
#define K_TOTAL 8192
#define TM 64
#define TN 64
#define BK 64
#define KITERS (K_TOTAL / BK)   // 128

typedef __attribute__((ext_vector_type(4))) float f32x4;
typedef __attribute__((ext_vector_type(8))) short s16x8;
typedef __attribute__((ext_vector_type(2))) int i32x2;

// pack two fp32 -> two bf16 (truncation) in one v_perm_b32
__device__ __forceinline__ int pk(float a, float b) {
    return (int)__builtin_amdgcn_perm(__float_as_uint(b), __float_as_uint(a), 0x07060302u);
}

// barrier with LDS-visibility only: does NOT drain vmcnt, so global
// prefetch loads issued before it remain in flight.
__device__ __forceinline__ void barrier_lds() {
    asm volatile("s_waitcnt lgkmcnt(0)\n\ts_barrier" ::: "memory");
}

__global__ __launch_bounds__(256, 2)
void abstract_linear_kernel(const float* __restrict__ x,
                            const float* __restrict__ low,
                            const float* __restrict__ high,
                            const float* __restrict__ W,
                            const float* __restrict__ bias,
                            float* __restrict__ out) {
    // XOR-swizzled bf16 tiles: element (row,k) at row*BK + ((k/8)^(row&7))*8 + k%8
    __shared__ __align__(16) unsigned short As[2][TM * BK];   // 2 x 8 KB
    __shared__ __align__(16) unsigned short Bs[2][TN * BK];   // 2 x 8 KB

    const int t  = threadIdx.x;
    const int bx = blockIdx.x;
    const int n0 = (bx & 127) * TN;   // bx, bx+128, bx+256, bx+384 share W tile & XCD
    const int m_tile = bx >> 7;       // 0..3
    const int m0 = m_tile * TM;
    const bool do_bounds = (m_tile == 0);

    // coalesced staging map: thread t -> rows j*16 + g, cols sg*4..sg*4+3
    const int g  = t >> 4;            // 0..15
    const int sg = t & 15;            // 0..15

    const float* xg = x + (size_t)(m0 + g) * K_TOTAL + sg * 4;
    const float* wg = W + (size_t)(n0 + g) * K_TOTAL + sg * 4;
    const float* lg = low  + sg * 4;
    const float* hg = high + sg * 4;

    // wave / fragment mapping: 4 waves 2x2, wave tile 32x32
    const int wave = t >> 6;
    const int lane = t & 63;
    const int wm  = wave >> 1;
    const int wn  = wave & 1;
    const int l15 = lane & 15;
    const int lq  = lane >> 4;

    f32x4 acc[2][2];
#pragma unroll
    for (int i = 0; i < 2; ++i)
#pragma unroll
        for (int j = 0; j < 2; ++j)
            acc[i][j] = (f32x4){0.f, 0.f, 0.f, 0.f};

    // bounds accumulators: P[j]/R[j] for W row j*16+g, this thread's 4 cols
    float P[4] = {0.f, 0.f, 0.f, 0.f};
    float R[4] = {0.f, 0.f, 0.f, 0.f};

    // 4-slot register pipeline (slot s holds tile t with t%4 == s)
    f32x4 a_reg[4][4], w_reg[4][4], lo_reg[4], hi_reg[4];

    auto issue = [&](int sl, int it) {
        const int kb = it * BK;
#pragma unroll
        for (int j = 0; j < 4; ++j)
            a_reg[sl][j] = *(const f32x4*)(xg + (size_t)j * 16 * K_TOTAL + kb);
#pragma unroll
        for (int j = 0; j < 4; ++j)
            w_reg[sl][j] = *(const f32x4*)(wg + (size_t)j * 16 * K_TOTAL + kb);
        if (do_bounds) {
            lo_reg[sl] = *(const f32x4*)(lg + kb);
            hi_reg[sl] = *(const f32x4*)(hg + kb);
        }
    };

    const int a_chunk = sg >> 1;      // 16B chunk within row
    const int a_half  = sg & 1;       // 8B half within chunk

    auto convert_write = [&](int sl, int buf) {
#pragma unroll
        for (int j = 0; j < 4; ++j) {
            f32x4 u = a_reg[sl][j];
            i32x2 d;
            d[0] = pk(u[0], u[1]);
            d[1] = pk(u[2], u[3]);
            int row = j * 16 + g;
            int pos = a_chunk ^ (row & 7);
            *(i32x2*)&As[buf][row * BK + pos * 8 + a_half * 4] = d;
        }
#pragma unroll
        for (int j = 0; j < 4; ++j) {
            f32x4 u = w_reg[sl][j];
            i32x2 d;
            d[0] = pk(u[0], u[1]);
            d[1] = pk(u[2], u[3]);
            int row = j * 16 + g;
            int pos = a_chunk ^ (row & 7);
            *(i32x2*)&Bs[buf][row * BK + pos * 8 + a_half * 4] = d;
        }
        if (do_bounds) {
            f32x4 l = lo_reg[sl], h = hi_reg[sl];
#pragma unroll
            for (int j = 0; j < 4; ++j) {
                f32x4 w = w_reg[sl][j];
#pragma unroll
                for (int e = 0; e < 4; ++e) {
                    float wv = w[e];
                    P[j] = fmaf(wv,        l[e] + h[e], P[j]);
                    R[j] = fmaf(fabsf(wv), h[e] - l[e], R[j]);
                }
            }
        }
    };

    auto mfma_tile = [&](int buf) {
#pragma unroll
        for (int s = 0; s < 2; ++s) {
            s16x8 af[2], bf[2];
#pragma unroll
            for (int mi = 0; mi < 2; ++mi) {
                int row = wm * 32 + mi * 16 + l15;
                int pos = (s * 4 + lq) ^ (row & 7);
                af[mi] = *(const s16x8*)&As[buf][row * BK + pos * 8];
            }
#pragma unroll
            for (int ni = 0; ni < 2; ++ni) {
                int row = wn * 32 + ni * 16 + l15;
                int pos = (s * 4 + lq) ^ (row & 7);
                bf[ni] = *(const s16x8*)&Bs[buf][row * BK + pos * 8];
            }
#pragma unroll
            for (int mi = 0; mi < 2; ++mi)
#pragma unroll
                for (int ni = 0; ni < 2; ++ni)
                    acc[mi][ni] = __builtin_amdgcn_mfma_f32_16x16x32_bf16(
                        af[mi], bf[ni], acc[mi][ni], 0, 0, 0);
        }
    };

    // ---- prologue: tiles 0..3 in flight; tile 0 staged to LDS buf 0 ----
    issue(0, 0);
    issue(1, 1);
    issue(2, 2);
    issue(3, 3);
    convert_write(0, 0);
    barrier_lds();

    // ---- main pipeline: phase t = {issue(slot t&3, tile t+4); mfma(buf t&1);
    //      convert_write(slot (t+1)&3, buf (t+1)&1); barrier} — the cw waits
    //      on loads issued 3 phases earlier. Unrolled x4, indices literal.
    for (int it = 0; it < KITERS - 4; it += 4) {
        issue(0, it + 4);
        mfma_tile(0);
        convert_write(1, 1);
        barrier_lds();

        issue(1, it + 5);
        mfma_tile(1);
        convert_write(2, 0);
        barrier_lds();

        issue(2, it + 6);
        mfma_tile(0);
        convert_write(3, 1);
        barrier_lds();

        issue(3, it + 7);
        mfma_tile(1);
        convert_write(0, 0);
        barrier_lds();
    }
    // tail: tiles 124..127 already in flight / staged
    mfma_tile(0);
    convert_write(1, 1);
    barrier_lds();
    mfma_tile(1);
    convert_write(2, 0);
    barrier_lds();
    mfma_tile(0);
    convert_write(3, 1);
    barrier_lds();
    mfma_tile(1);

    // ---- epilogue: y = acc + b  (C/D layout: col = lane&15, row = lq*4+reg) ----
#pragma unroll
    for (int ni = 0; ni < 2; ++ni) {
        int go = n0 + wn * 32 + ni * 16 + l15;
        float bv = bias[go];
#pragma unroll
        for (int mi = 0; mi < 2; ++mi) {
            int gr = m0 + wm * 32 + mi * 16 + lq * 4;
#pragma unroll
            for (int r = 0; r < 4; ++r)
                out[(size_t)(gr + r) * N_TOTAL + go] = acc[mi][ni][r] + bv;
        }
    }

    // ---- epilogue: bounds (reduce over the 16 lanes sharing t>>4) ----
    if (do_bounds) {
#pragma unroll
        for (int j = 0; j < 4; ++j) {
            float p = P[j], r = R[j];
            p += __shfl_xor(p, 1);
            p += __shfl_xor(p, 2);
            p += __shfl_xor(p, 4);
            p += __shfl_xor(p, 8);
            r += __shfl_xor(r, 1);
            r += __shfl_xor(r, 2);
            r += __shfl_xor(r, 4);
            r += __shfl_xor(r, 8);
            if (sg == 0) {
                int o = n0 + j * 16 + g;
                float bv = bias[o];
                out[(size_t)M_TOTAL * N_TOTAL + o]           = 0.5f * (p - r) + bv;
                out[(size_t)M_TOTAL * N_TOTAL + N_TOTAL + o] = 0.5f * (p + r) + bv;
            }
        }
    }
}

extern "C" void kernel_launch(void* const* d_in, const int* in_sizes, int n_in,
                              void* d_out, int out_size, void* d_ws, size_t ws_size,
                              hipStream_t stream) {
    const float* x    = (const float*)d_in[0];
    const float* low  = (const float*)d_in[1];
    const float* high = (const float*)d_in[2];
    const float* W    = (const float*)d_in[3];
    const float* b    = (const float*)d_in[4];
    float* out = (float*)d_out;

    dim3 grid(4 * (N_TOTAL / TN));   // 512 blocks: 4 M-tiles x 128 N-tiles
    dim3 block(256);
    hipLaunchKernelGGL(abstract_linear_kernel, grid, block, 0, stream,
                       x, low, high, W, b, out);
}